// Round 1
// baseline (1191.033 us; speedup 1.0000x reference)
//
#include <hip/hip_runtime.h>
#include <hip/hip_bf16.h>
#include <cstdint>

#define N_NODES 100000
#define N_EDGES 3200000

// ---- float <-> order-preserving unsigned (for signed-float atomic max) ----
__device__ __forceinline__ unsigned flipf(float f) {
    unsigned u = __float_as_uint(f);
    return (u & 0x80000000u) ? ~u : (u | 0x80000000u);
}
__device__ __forceinline__ float unflipf(unsigned v) {
    unsigned u = (v & 0x80000000u) ? (v & 0x7FFFFFFFu) : ~v;
    return __uint_as_float(u);
}

// ---------------- Layer 1 edge scatter: dim-2 sum + dim-2 max ----------------
__global__ __launch_bounds__(256) void edge1_kernel(
        const int* __restrict__ ei, const float* __restrict__ norm,
        const float2* __restrict__ x, float* __restrict__ agg1s,
        unsigned* __restrict__ agg1x) {
    int e = blockIdx.x * blockDim.x + threadIdx.x;
    if (e >= N_EDGES) return;
    int s = ei[e];
    int d = ei[N_EDGES + e];
    float w = norm[e];
    float2 xs = x[s];
    atomicAdd(&agg1s[2 * d],     xs.x * w);
    atomicAdd(&agg1s[2 * d + 1], xs.y * w);
    atomicMax(&agg1x[2 * d],     flipf(xs.x));
    atomicMax(&agg1x[2 * d + 1], flipf(xs.y));
}

// -------- Node kernel 1: h1 = [relu(wsage1) | relu(msage1)], z2 = h1@W2m_l^T --------
// shared layout: w1m_l[48] b1m[24]@48 w1m_r[72..120] w1x_l[120..136] b1x[136..144]
//                w1x_r[144..160] w2m_l[160..544]
__global__ __launch_bounds__(256) void node1_kernel(
        const float2* __restrict__ x,
        const float* __restrict__ agg1s, const unsigned* __restrict__ agg1x,
        const float* __restrict__ w1m_l, const float* __restrict__ b1m,
        const float* __restrict__ w1m_r,
        const float* __restrict__ w1x_l, const float* __restrict__ b1x,
        const float* __restrict__ w1x_r,
        const float* __restrict__ w2m_l,
        float* __restrict__ h1, float* __restrict__ z2) {
    __shared__ float sw[544];
    for (int t = threadIdx.x; t < 544; t += blockDim.x) {
        float v;
        if (t < 48)       v = w1m_l[t];
        else if (t < 72)  v = b1m[t - 48];
        else if (t < 120) v = w1m_r[t - 72];
        else if (t < 136) v = w1x_l[t - 120];
        else if (t < 144) v = b1x[t - 136];
        else if (t < 160) v = w1x_r[t - 144];
        else              v = w2m_l[t - 160];
        sw[t] = v;
    }
    __syncthreads();

    int i = blockIdx.x * blockDim.x + threadIdx.x;
    if (i >= N_NODES) return;

    float2 xi = x[i];
    float a0 = agg1s[2 * i], a1 = agg1s[2 * i + 1];
    unsigned m0u = agg1x[2 * i], m1u = agg1x[2 * i + 1];
    float m0 = m0u ? unflipf(m0u) : 0.0f;   // sentinel 0 == empty segment -> 0
    float m1 = m1u ? unflipf(m1u) : 0.0f;

    float hh[32];
#pragma unroll
    for (int k = 0; k < 24; k++) {
        float v = sw[48 + k] + sw[2 * k] * a0 + sw[2 * k + 1] * a1
                + sw[72 + 2 * k] * xi.x + sw[72 + 2 * k + 1] * xi.y;
        hh[k] = fmaxf(v, 0.0f);
    }
#pragma unroll
    for (int k = 0; k < 8; k++) {
        float v = sw[136 + k] + sw[120 + 2 * k] * m0 + sw[120 + 2 * k + 1] * m1
                + sw[144 + 2 * k] * xi.x + sw[144 + 2 * k + 1] * xi.y;
        hh[24 + k] = fmaxf(v, 0.0f);
    }

    float4* h1v = (float4*)(h1 + (size_t)i * 32);
#pragma unroll
    for (int q = 0; q < 8; q++)
        h1v[q] = make_float4(hh[4 * q], hh[4 * q + 1], hh[4 * q + 2], hh[4 * q + 3]);

#pragma unroll
    for (int j = 0; j < 12; j++) {
        float v = 0.0f;
#pragma unroll
        for (int k = 0; k < 32; k++) v += hh[k] * sw[160 + j * 32 + k];
        z2[(size_t)i * 12 + j] = v;
    }
}

// ------------- Layer 2 edge scatter: 32 lanes per edge -------------
// lanes f=0..31: atomic int-max of h1[src][f] into agg2x[dst][f]  (h1 >= 0)
// lanes f<12:    atomicAdd z2[src][f]*norm into agg2s[dst][f]
__global__ __launch_bounds__(256) void edge2_kernel(
        const int* __restrict__ ei, const float* __restrict__ norm,
        const float* __restrict__ h1, const float* __restrict__ z2,
        float* __restrict__ agg2s, float* __restrict__ agg2x) {
    int tid = blockIdx.x * blockDim.x + threadIdx.x;
    int e = tid >> 5;
    int f = tid & 31;
    if (e >= N_EDGES) return;
    int s = ei[e];
    int d = ei[N_EDGES + e];
    float v = h1[(size_t)s * 32 + f];
    atomicMax((int*)&agg2x[(size_t)d * 32 + f], __float_as_int(v));
    if (f < 12) {
        float w = norm[e];
        atomicAdd(&agg2s[(size_t)d * 12 + f], z2[(size_t)s * 12 + f] * w);
    }
}

// ------------- Node kernel 2: layer-2 epilogue + MLP head -> out -------------
// shared: b2m[0..12) w2m_r[12..396) w2x_l[396..524) b2x[524..528) w2x_r[528..656)
//         w3[656..784) b3[784..792) w4[792..832) b4[832..837) w5[837..842) b5[842]
__global__ __launch_bounds__(256) void node2_kernel(
        const float* __restrict__ h1,
        const float* __restrict__ agg2s, const float* __restrict__ agg2x,
        const float* __restrict__ b2m, const float* __restrict__ w2m_r,
        const float* __restrict__ w2x_l, const float* __restrict__ b2x,
        const float* __restrict__ w2x_r,
        const float* __restrict__ w3, const float* __restrict__ b3,
        const float* __restrict__ w4, const float* __restrict__ b4,
        const float* __restrict__ w5, const float* __restrict__ b5,
        float* __restrict__ out) {
    __shared__ float sw[843];
    for (int t = threadIdx.x; t < 843; t += blockDim.x) {
        float v;
        if (t < 12)       v = b2m[t];
        else if (t < 396) v = w2m_r[t - 12];
        else if (t < 524) v = w2x_l[t - 396];
        else if (t < 528) v = b2x[t - 524];
        else if (t < 656) v = w2x_r[t - 528];
        else if (t < 784) v = w3[t - 656];
        else if (t < 792) v = b3[t - 784];
        else if (t < 832) v = w4[t - 792];
        else if (t < 837) v = b4[t - 832];
        else if (t < 842) v = w5[t - 837];
        else              v = b5[0];
        sw[t] = v;
    }
    __syncthreads();

    int i = blockIdx.x * blockDim.x + threadIdx.x;
    if (i >= N_NODES) return;

    float hh[32], ax[32];
    const float4* h1v = (const float4*)(h1 + (size_t)i * 32);
    const float4* axv = (const float4*)(agg2x + (size_t)i * 32);
#pragma unroll
    for (int q = 0; q < 8; q++) {
        float4 a = h1v[q];
        hh[4 * q] = a.x; hh[4 * q + 1] = a.y; hh[4 * q + 2] = a.z; hh[4 * q + 3] = a.w;
        float4 b = axv[q];
        ax[4 * q] = b.x; ax[4 * q + 1] = b.y; ax[4 * q + 2] = b.z; ax[4 * q + 3] = b.w;
    }

    float h2[16];
#pragma unroll
    for (int j = 0; j < 12; j++) {
        float v = agg2s[(size_t)i * 12 + j] + sw[j];
#pragma unroll
        for (int k = 0; k < 32; k++) v += hh[k] * sw[12 + j * 32 + k];
        h2[j] = fmaxf(v, 0.0f);
    }
#pragma unroll
    for (int j = 0; j < 4; j++) {
        float v = sw[524 + j];
#pragma unroll
        for (int k = 0; k < 32; k++)
            v += ax[k] * sw[396 + j * 32 + k] + hh[k] * sw[528 + j * 32 + k];
        h2[12 + j] = fmaxf(v, 0.0f);
    }

    float t3[8];
#pragma unroll
    for (int j = 0; j < 8; j++) {
        float v = sw[784 + j];
#pragma unroll
        for (int k = 0; k < 16; k++) v += h2[k] * sw[656 + j * 16 + k];
        t3[j] = fmaxf(v, 0.0f);
    }
    float t4[5];
#pragma unroll
    for (int j = 0; j < 5; j++) {
        float v = sw[832 + j];
#pragma unroll
        for (int k = 0; k < 8; k++) v += t3[k] * sw[792 + j * 8 + k];
        t4[j] = fmaxf(v, 0.0f);
    }
    float o = sw[842];
#pragma unroll
    for (int k = 0; k < 5; k++) o += t4[k] * sw[837 + k];
    out[i] = o;
}

extern "C" void kernel_launch(void* const* d_in, const int* in_sizes, int n_in,
                              void* d_out, int out_size, void* d_ws, size_t ws_size,
                              hipStream_t stream) {
    const float* x     = (const float*)d_in[0];
    const int*   ei    = (const int*)d_in[1];
    const float* norm  = (const float*)d_in[2];
    const float* w1m_l = (const float*)d_in[3];
    const float* b1m   = (const float*)d_in[4];
    const float* w1m_r = (const float*)d_in[5];
    const float* w1x_l = (const float*)d_in[6];
    const float* b1x   = (const float*)d_in[7];
    const float* w1x_r = (const float*)d_in[8];
    const float* w2m_l = (const float*)d_in[9];
    const float* b2m   = (const float*)d_in[10];
    const float* w2m_r = (const float*)d_in[11];
    const float* w2x_l = (const float*)d_in[12];
    const float* b2x   = (const float*)d_in[13];
    const float* w2x_r = (const float*)d_in[14];
    const float* w3    = (const float*)d_in[15];
    const float* b3    = (const float*)d_in[16];
    const float* w4    = (const float*)d_in[17];
    const float* b4    = (const float*)d_in[18];
    const float* w5    = (const float*)d_in[19];
    const float* b5    = (const float*)d_in[20];
    float* out = (float*)d_out;

    const size_t N = N_NODES;
    float*    ws    = (float*)d_ws;
    float*    agg1s = ws;                         // 2N
    unsigned* agg1x = (unsigned*)(ws + 2 * N);    // 2N
    float*    agg2s = ws + 4 * N;                 // 12N
    float*    agg2x = ws + 16 * N;                // 32N
    float*    h1    = ws + 48 * N;                // 32N
    float*    z2    = ws + 80 * N;                // 12N  (total 92N floats = 36.8 MB)

    // zero all aggregation buffers in one shot (agg1x sentinel 0 == "empty")
    hipMemsetAsync(d_ws, 0, 48 * N * sizeof(float), stream);

    edge1_kernel<<<(N_EDGES + 255) / 256, 256, 0, stream>>>(ei, norm, (const float2*)x,
                                                            agg1s, agg1x);
    node1_kernel<<<(N_NODES + 255) / 256, 256, 0, stream>>>((const float2*)x, agg1s, agg1x,
                                                            w1m_l, b1m, w1m_r,
                                                            w1x_l, b1x, w1x_r,
                                                            w2m_l, h1, z2);
    edge2_kernel<<<(N_EDGES * 32) / 256, 256, 0, stream>>>(ei, norm, h1, z2, agg2s, agg2x);
    node2_kernel<<<(N_NODES + 255) / 256, 256, 0, stream>>>(h1, agg2s, agg2x,
                                                            b2m, w2m_r, w2x_l, b2x, w2x_r,
                                                            w3, b3, w4, b4, w5, b5, out);
}

// Round 2
// 1123.064 us; speedup vs baseline: 1.0605x; 1.0605x over previous
//
#include <hip/hip_runtime.h>
#include <hip/hip_bf16.h>
#include <cstdint>

#define N_NODES 100000
#define N_EDGES 3200000
#define NBUCK   391          // ceil(N_NODES / 256)
#define K13_BLOCKS 512
#define K13_CHUNK  6250      // 512 * 6250 = 3.2M exactly

// ---- float <-> order-preserving unsigned (signed-float max via uint max) ----
__device__ __forceinline__ unsigned flipf(float f) {
    unsigned u = __float_as_uint(f);
    return (u & 0x80000000u) ? ~u : (u | 0x80000000u);
}
__device__ __forceinline__ float unflipf(unsigned v) {
    unsigned u = (v & 0x80000000u) ? (v & 0x7FFFFFFFu) : ~v;
    return __uint_as_float(u);
}

// ---------------- K1: per-bucket edge counts (dst >> 8) ----------------
__global__ __launch_bounds__(256) void k1_count(const int* __restrict__ ei,
                                                int* __restrict__ total) {
    __shared__ int hist[NBUCK];
    for (int t = threadIdx.x; t < NBUCK; t += 256) hist[t] = 0;
    __syncthreads();
    int e0 = blockIdx.x * K13_CHUNK;
    for (int k = threadIdx.x; k < K13_CHUNK; k += 256) {
        int e = e0 + k;
        if (e < N_EDGES) {
            int d = ei[N_EDGES + e];
            atomicAdd(&hist[d >> 8], 1);
        }
    }
    __syncthreads();
    for (int t = threadIdx.x; t < NBUCK; t += 256) {
        int c = hist[t];
        if (c) atomicAdd(&total[t], c);
    }
}

// ---------------- K2: exclusive scan of totals -> bucketBase, cursor ----------------
__global__ __launch_bounds__(512) void k2_scan(const int* __restrict__ total,
                                               int* __restrict__ bucketBase,
                                               int* __restrict__ cursor) {
    __shared__ int s[512];
    int t = threadIdx.x;
    int v = (t < NBUCK) ? total[t] : 0;
    s[t] = v;
    __syncthreads();
    for (int off = 1; off < 512; off <<= 1) {
        int u = (t >= off) ? s[t - off] : 0;
        __syncthreads();
        s[t] += u;
        __syncthreads();
    }
    if (t < NBUCK) {
        int ex = s[t] - v;
        bucketBase[t] = ex;
        cursor[t] = ex;
        if (t == NBUCK - 1) bucketBase[NBUCK] = s[t];
    }
}

// ---------------- K3: scatter edges into bucket-contiguous packed records ----------------
// record: int2 { (src<<8) | (dst&255), bits(norm) }
__global__ __launch_bounds__(256) void k3_scatter(const int* __restrict__ ei,
                                                  const float* __restrict__ norm,
                                                  int* __restrict__ cursor,
                                                  int2* __restrict__ ebuf) {
    __shared__ int hist[NBUCK];
    __shared__ int base_l[NBUCK];
    __shared__ int run[NBUCK];
    for (int t = threadIdx.x; t < NBUCK; t += 256) { hist[t] = 0; run[t] = 0; }
    __syncthreads();
    int e0 = blockIdx.x * K13_CHUNK;
    for (int k = threadIdx.x; k < K13_CHUNK; k += 256) {
        int e = e0 + k;
        if (e < N_EDGES) atomicAdd(&hist[ei[N_EDGES + e] >> 8], 1);
    }
    __syncthreads();
    for (int t = threadIdx.x; t < NBUCK; t += 256) {
        int c = hist[t];
        base_l[t] = c ? atomicAdd(&cursor[t], c) : 0;
    }
    __syncthreads();
    for (int k = threadIdx.x; k < K13_CHUNK; k += 256) {
        int e = e0 + k;
        if (e < N_EDGES) {
            int s = ei[e];
            int d = ei[N_EDGES + e];
            float w = norm[e];
            int b = d >> 8;
            int r = atomicAdd(&run[b], 1);
            ebuf[base_l[b] + r] = make_int2((s << 8) | (d & 255), __float_as_int(w));
        }
    }
}

// ---------------- K4: layer-1 aggregate (LDS) + fused node1 -> h1, z2 ----------------
// sw layout: w1m_l[0..48) b1m[48..72) w1m_r[72..120) w1x_l[120..136) b1x[136..144)
//            w1x_r[144..160) w2m_l[160..544)
__global__ __launch_bounds__(256) void k4_layer1(
        const float2* __restrict__ x, const int2* __restrict__ ebuf,
        const int* __restrict__ bucketBase,
        const float* __restrict__ w1m_l, const float* __restrict__ b1m,
        const float* __restrict__ w1m_r,
        const float* __restrict__ w1x_l, const float* __restrict__ b1x,
        const float* __restrict__ w1x_r,
        const float* __restrict__ w2m_l,
        float* __restrict__ h1, float* __restrict__ z2) {
    __shared__ float sw[544];
    __shared__ float s_sum[512];
    __shared__ unsigned s_max[512];
    for (int t = threadIdx.x; t < 544; t += 256) {
        float v;
        if (t < 48)       v = w1m_l[t];
        else if (t < 72)  v = b1m[t - 48];
        else if (t < 120) v = w1m_r[t - 72];
        else if (t < 136) v = w1x_l[t - 120];
        else if (t < 144) v = b1x[t - 136];
        else if (t < 160) v = w1x_r[t - 144];
        else              v = w2m_l[t - 160];
        sw[t] = v;
    }
    for (int t = threadIdx.x; t < 512; t += 256) { s_sum[t] = 0.0f; s_max[t] = 0u; }
    __syncthreads();

    int b = blockIdx.x;
    int eBeg = bucketBase[b], eEnd = bucketBase[b + 1];
    for (int e = eBeg + threadIdx.x; e < eEnd; e += 256) {
        int2 rec = ebuf[e];
        int src = rec.x >> 8;
        int local = rec.x & 255;
        float w = __int_as_float(rec.y);
        float2 xs = x[src];
        atomicAdd(&s_sum[2 * local],     xs.x * w);
        atomicAdd(&s_sum[2 * local + 1], xs.y * w);
        atomicMax(&s_max[2 * local],     flipf(xs.x));
        atomicMax(&s_max[2 * local + 1], flipf(xs.y));
    }
    __syncthreads();

    int t = threadIdx.x;
    int i = b * 256 + t;
    if (i >= N_NODES) return;

    float2 xi = x[i];
    float a0 = s_sum[2 * t], a1 = s_sum[2 * t + 1];
    unsigned m0u = s_max[2 * t], m1u = s_max[2 * t + 1];
    float m0 = m0u ? unflipf(m0u) : 0.0f;   // sentinel 0 == empty segment -> 0
    float m1 = m1u ? unflipf(m1u) : 0.0f;

    float hh[32];
#pragma unroll
    for (int k = 0; k < 24; k++) {
        float v = sw[48 + k] + sw[2 * k] * a0 + sw[2 * k + 1] * a1
                + sw[72 + 2 * k] * xi.x + sw[72 + 2 * k + 1] * xi.y;
        hh[k] = fmaxf(v, 0.0f);
    }
#pragma unroll
    for (int k = 0; k < 8; k++) {
        float v = sw[136 + k] + sw[120 + 2 * k] * m0 + sw[120 + 2 * k + 1] * m1
                + sw[144 + 2 * k] * xi.x + sw[144 + 2 * k + 1] * xi.y;
        hh[24 + k] = fmaxf(v, 0.0f);
    }

    float4* h1v = (float4*)(h1 + (size_t)i * 32);
#pragma unroll
    for (int q = 0; q < 8; q++)
        h1v[q] = make_float4(hh[4 * q], hh[4 * q + 1], hh[4 * q + 2], hh[4 * q + 3]);

#pragma unroll
    for (int j = 0; j < 12; j++) {
        float v = 0.0f;
#pragma unroll
        for (int k = 0; k < 32; k++) v += hh[k] * sw[160 + j * 32 + k];
        z2[(size_t)i * 12 + j] = v;
    }
}

// ---------------- K5: layer-2 aggregate (LDS, 32 lanes/edge) + fused node2 + MLP ----------------
// sw layout: b2m[0..12) w2m_r[12..396) w2x_l[396..524) b2x[524..528) w2x_r[528..656)
//            w3[656..784) b3[784..792) w4[792..832) b4[832..837) w5[837..842) b5[842]
__global__ __launch_bounds__(256) void k5_layer2(
        const float* __restrict__ h1, const float* __restrict__ z2,
        const int2* __restrict__ ebuf, const int* __restrict__ bucketBase,
        const float* __restrict__ b2m, const float* __restrict__ w2m_r,
        const float* __restrict__ w2x_l, const float* __restrict__ b2x,
        const float* __restrict__ w2x_r,
        const float* __restrict__ w3, const float* __restrict__ b3,
        const float* __restrict__ w4, const float* __restrict__ b4,
        const float* __restrict__ w5, const float* __restrict__ b5,
        float* __restrict__ out) {
    __shared__ float sw[843];
    __shared__ float    s2s[256 * 12];   // 12 KB
    __shared__ unsigned s2x[256 * 32];   // 32 KB (h1 >= 0 -> uint-ordered)
    for (int t = threadIdx.x; t < 843; t += 256) {
        float v;
        if (t < 12)       v = b2m[t];
        else if (t < 396) v = w2m_r[t - 12];
        else if (t < 524) v = w2x_l[t - 396];
        else if (t < 528) v = b2x[t - 524];
        else if (t < 656) v = w2x_r[t - 528];
        else if (t < 784) v = w3[t - 656];
        else if (t < 792) v = b3[t - 784];
        else if (t < 832) v = w4[t - 792];
        else if (t < 837) v = b4[t - 832];
        else if (t < 842) v = w5[t - 837];
        else              v = b5[0];
        sw[t] = v;
    }
    for (int t = threadIdx.x; t < 256 * 12; t += 256) s2s[t] = 0.0f;
    for (int t = threadIdx.x; t < 256 * 32; t += 256) s2x[t] = 0u;
    __syncthreads();

    int b = blockIdx.x;
    int eBeg = bucketBase[b], eEnd = bucketBase[b + 1];
    int f  = threadIdx.x & 31;
    int eg = threadIdx.x >> 5;           // 8 edge-groups per block
    for (int e = eBeg + eg; e < eEnd; e += 8) {
        int2 rec = ebuf[e];              // broadcast within the 32-lane group
        int src = rec.x >> 8;
        int local = rec.x & 255;
        float w = __int_as_float(rec.y);
        float v = h1[(size_t)src * 32 + f];           // 128B coalesced row gather
        atomicMax(&s2x[local * 32 + f], __float_as_uint(v));
        if (f < 12) {
            float z = z2[(size_t)src * 12 + f];
            atomicAdd(&s2s[local * 12 + f], z * w);
        }
    }
    __syncthreads();

    int t = threadIdx.x;
    int i = b * 256 + t;
    if (i >= N_NODES) return;

    float hh[32], ax[32];
    const float4* h1v = (const float4*)(h1 + (size_t)i * 32);
#pragma unroll
    for (int q = 0; q < 8; q++) {
        float4 a = h1v[q];
        hh[4 * q] = a.x; hh[4 * q + 1] = a.y; hh[4 * q + 2] = a.z; hh[4 * q + 3] = a.w;
    }
#pragma unroll
    for (int k = 0; k < 32; k++) ax[k] = __uint_as_float(s2x[t * 32 + k]);

    float h2[16];
#pragma unroll
    for (int j = 0; j < 12; j++) {
        float v = s2s[t * 12 + j] + sw[j];
#pragma unroll
        for (int k = 0; k < 32; k++) v += hh[k] * sw[12 + j * 32 + k];
        h2[j] = fmaxf(v, 0.0f);
    }
#pragma unroll
    for (int j = 0; j < 4; j++) {
        float v = sw[524 + j];
#pragma unroll
        for (int k = 0; k < 32; k++)
            v += ax[k] * sw[396 + j * 32 + k] + hh[k] * sw[528 + j * 32 + k];
        h2[12 + j] = fmaxf(v, 0.0f);
    }

    float t3[8];
#pragma unroll
    for (int j = 0; j < 8; j++) {
        float v = sw[784 + j];
#pragma unroll
        for (int k = 0; k < 16; k++) v += h2[k] * sw[656 + j * 16 + k];
        t3[j] = fmaxf(v, 0.0f);
    }
    float t4[5];
#pragma unroll
    for (int j = 0; j < 5; j++) {
        float v = sw[832 + j];
#pragma unroll
        for (int k = 0; k < 8; k++) v += t3[k] * sw[792 + j * 8 + k];
        t4[j] = fmaxf(v, 0.0f);
    }
    float o = sw[842];
#pragma unroll
    for (int k = 0; k < 5; k++) o += t4[k] * sw[837 + k];
    out[i] = o;
}

extern "C" void kernel_launch(void* const* d_in, const int* in_sizes, int n_in,
                              void* d_out, int out_size, void* d_ws, size_t ws_size,
                              hipStream_t stream) {
    const float* x     = (const float*)d_in[0];
    const int*   ei    = (const int*)d_in[1];
    const float* norm  = (const float*)d_in[2];
    const float* w1m_l = (const float*)d_in[3];
    const float* b1m   = (const float*)d_in[4];
    const float* w1m_r = (const float*)d_in[5];
    const float* w1x_l = (const float*)d_in[6];
    const float* b1x   = (const float*)d_in[7];
    const float* w1x_r = (const float*)d_in[8];
    const float* w2m_l = (const float*)d_in[9];
    const float* b2m   = (const float*)d_in[10];
    const float* w2m_r = (const float*)d_in[11];
    const float* w2x_l = (const float*)d_in[12];
    const float* b2x   = (const float*)d_in[13];
    const float* w2x_r = (const float*)d_in[14];
    const float* w3    = (const float*)d_in[15];
    const float* b3    = (const float*)d_in[16];
    const float* w4    = (const float*)d_in[17];
    const float* b4    = (const float*)d_in[18];
    const float* w5    = (const float*)d_in[19];
    const float* b5    = (const float*)d_in[20];
    float* out = (float*)d_out;

    // workspace layout
    char* ws = (char*)d_ws;
    int2*  ebuf       = (int2*)ws;                              // 25.6 MB
    float* h1         = (float*)(ws + (size_t)N_EDGES * 8);     // 12.8 MB
    float* z2         = h1 + (size_t)N_NODES * 32;              //  4.8 MB
    int*   total      = (int*)(z2 + (size_t)N_NODES * 12);      // NBUCK
    int*   bucketBase = total + NBUCK;                          // NBUCK+1
    int*   cursor     = bucketBase + NBUCK + 1;                 // NBUCK

    hipMemsetAsync(total, 0, NBUCK * sizeof(int), stream);

    k1_count  <<<K13_BLOCKS, 256, 0, stream>>>(ei, total);
    k2_scan   <<<1, 512, 0, stream>>>(total, bucketBase, cursor);
    k3_scatter<<<K13_BLOCKS, 256, 0, stream>>>(ei, norm, cursor, ebuf);
    k4_layer1 <<<NBUCK, 256, 0, stream>>>((const float2*)x, ebuf, bucketBase,
                                          w1m_l, b1m, w1m_r, w1x_l, b1x, w1x_r,
                                          w2m_l, h1, z2);
    k5_layer2 <<<NBUCK, 256, 0, stream>>>(h1, z2, ebuf, bucketBase,
                                          b2m, w2m_r, w2x_l, b2x, w2x_r,
                                          w3, b3, w4, b4, w5, b5, out);
}

// Round 3
// 560.515 us; speedup vs baseline: 2.1249x; 2.0036x over previous
//
#include <hip/hip_runtime.h>
#include <hip/hip_bf16.h>
#include <cstdint>

#define N_NODES 100000
#define N_EDGES 3200000
#define NBUCK   391          // ceil(N_NODES / 256)
#define NPAD    (NBUCK * 256)
#define K13_BLOCKS 512
#define K13_CHUNK  6250      // 512 * 6250 = 3.2M exactly

// ---- float <-> order-preserving unsigned (signed-float max via uint max) ----
__device__ __forceinline__ unsigned flipf(float f) {
    unsigned u = __float_as_uint(f);
    return (u & 0x80000000u) ? ~u : (u | 0x80000000u);
}
__device__ __forceinline__ float unflipf(unsigned v) {
    unsigned u = (v & 0x80000000u) ? (v & 0x7FFFFFFFu) : ~v;
    return __uint_as_float(u);
}

// ---------------- K1: per-bucket edge counts (dst >> 8) ----------------
__global__ __launch_bounds__(256) void k1_count(const int* __restrict__ ei,
                                                int* __restrict__ total) {
    __shared__ int hist[NBUCK];
    for (int t = threadIdx.x; t < NBUCK; t += 256) hist[t] = 0;
    __syncthreads();
    int e0 = blockIdx.x * K13_CHUNK;
    for (int k = threadIdx.x; k < K13_CHUNK; k += 256) {
        int e = e0 + k;
        if (e < N_EDGES) atomicAdd(&hist[ei[N_EDGES + e] >> 8], 1);
    }
    __syncthreads();
    for (int t = threadIdx.x; t < NBUCK; t += 256) {
        int c = hist[t];
        if (c) atomicAdd(&total[t], c);
    }
}

// ---------------- K2: exclusive scan -> bucketBase, cursor ----------------
__global__ __launch_bounds__(512) void k2_scan(const int* __restrict__ total,
                                               int* __restrict__ bucketBase,
                                               int* __restrict__ cursor) {
    __shared__ int s[512];
    int t = threadIdx.x;
    int v = (t < NBUCK) ? total[t] : 0;
    s[t] = v;
    __syncthreads();
    for (int off = 1; off < 512; off <<= 1) {
        int u = (t >= off) ? s[t - off] : 0;
        __syncthreads();
        s[t] += u;
        __syncthreads();
    }
    if (t < NBUCK) {
        int ex = s[t] - v;
        bucketBase[t] = ex;
        cursor[t] = ex;
        if (t == NBUCK - 1) bucketBase[NBUCK] = s[t];
    }
}

// ---------------- K3: scatter edges into bucket-contiguous packed records ----------------
// record: int2 { (src<<8) | (dst&255), bits(norm) }
__global__ __launch_bounds__(256) void k3_scatter(const int* __restrict__ ei,
                                                  const float* __restrict__ norm,
                                                  int* __restrict__ cursor,
                                                  int2* __restrict__ ebuf) {
    __shared__ int hist[NBUCK];
    __shared__ int base_l[NBUCK];
    __shared__ int run[NBUCK];
    for (int t = threadIdx.x; t < NBUCK; t += 256) { hist[t] = 0; run[t] = 0; }
    __syncthreads();
    int e0 = blockIdx.x * K13_CHUNK;
    for (int k = threadIdx.x; k < K13_CHUNK; k += 256) {
        int e = e0 + k;
        if (e < N_EDGES) atomicAdd(&hist[ei[N_EDGES + e] >> 8], 1);
    }
    __syncthreads();
    for (int t = threadIdx.x; t < NBUCK; t += 256) {
        int c = hist[t];
        base_l[t] = c ? atomicAdd(&cursor[t], c) : 0;
    }
    __syncthreads();
    for (int k = threadIdx.x; k < K13_CHUNK; k += 256) {
        int e = e0 + k;
        if (e < N_EDGES) {
            int s = ei[e];
            int d = ei[N_EDGES + e];
            float w = norm[e];
            int b = d >> 8;
            int r = atomicAdd(&run[b], 1);
            ebuf[base_l[b] + r] = make_int2((s << 8) | (d & 255), __float_as_int(w));
        }
    }
}

// -------- K4a: layer-1 LDS aggregation, SPLIT=2 blocks per bucket, merge via coalesced atomics --------
__global__ __launch_bounds__(256) void k4a_agg1(
        const float2* __restrict__ x, const int2* __restrict__ ebuf,
        const int* __restrict__ bucketBase,
        float* __restrict__ agg1s, unsigned* __restrict__ agg1x) {
    __shared__ float    s_sum[512];
    __shared__ unsigned s_max[512];
    for (int t = threadIdx.x; t < 512; t += 256) { s_sum[t] = 0.0f; s_max[t] = 0u; }
    __syncthreads();

    int b = blockIdx.x >> 1, sp = blockIdx.x & 1;
    int eBeg = bucketBase[b], eEnd = bucketBase[b + 1];
    int half = (eEnd - eBeg + 1) >> 1;
    int beg = eBeg + sp * half;
    int end = min(eEnd, beg + half);

    int e = beg + threadIdx.x;
    for (; e + 768 < end; e += 1024) {
        int2 r0 = ebuf[e], r1 = ebuf[e + 256], r2 = ebuf[e + 512], r3 = ebuf[e + 768];
        float2 x0 = x[r0.x >> 8], x1 = x[r1.x >> 8], x2 = x[r2.x >> 8], x3 = x[r3.x >> 8];
        float w0 = __int_as_float(r0.y), w1 = __int_as_float(r1.y);
        float w2 = __int_as_float(r2.y), w3 = __int_as_float(r3.y);
        int l0 = (r0.x & 255) * 2, l1 = (r1.x & 255) * 2, l2 = (r2.x & 255) * 2, l3 = (r3.x & 255) * 2;
        atomicAdd(&s_sum[l0],     x0.x * w0); atomicAdd(&s_sum[l0 + 1], x0.y * w0);
        atomicAdd(&s_sum[l1],     x1.x * w1); atomicAdd(&s_sum[l1 + 1], x1.y * w1);
        atomicAdd(&s_sum[l2],     x2.x * w2); atomicAdd(&s_sum[l2 + 1], x2.y * w2);
        atomicAdd(&s_sum[l3],     x3.x * w3); atomicAdd(&s_sum[l3 + 1], x3.y * w3);
        atomicMax(&s_max[l0],     flipf(x0.x)); atomicMax(&s_max[l0 + 1], flipf(x0.y));
        atomicMax(&s_max[l1],     flipf(x1.x)); atomicMax(&s_max[l1 + 1], flipf(x1.y));
        atomicMax(&s_max[l2],     flipf(x2.x)); atomicMax(&s_max[l2 + 1], flipf(x2.y));
        atomicMax(&s_max[l3],     flipf(x3.x)); atomicMax(&s_max[l3 + 1], flipf(x3.y));
    }
    for (; e < end; e += 256) {
        int2 r = ebuf[e];
        float2 xs = x[r.x >> 8];
        float w = __int_as_float(r.y);
        int l = (r.x & 255) * 2;
        atomicAdd(&s_sum[l],     xs.x * w); atomicAdd(&s_sum[l + 1], xs.y * w);
        atomicMax(&s_max[l],     flipf(xs.x)); atomicMax(&s_max[l + 1], flipf(xs.y));
    }
    __syncthreads();

    int base = b * 512;
    for (int u = threadIdx.x; u < 512; u += 256) {
        float v = s_sum[u];
        if (v != 0.0f) atomicAdd(&agg1s[base + u], v);
        unsigned m = s_max[u];
        if (m) atomicMax(&agg1x[base + u], m);
    }
}

// -------- K4b: node1 epilogue: h1 = [relu(wsage1) | relu(msage1)], z2 = h1@W2m_l^T --------
__global__ __launch_bounds__(256) void k4b_node1(
        const float2* __restrict__ x,
        const float* __restrict__ agg1s, const unsigned* __restrict__ agg1x,
        const float* __restrict__ w1m_l, const float* __restrict__ b1m,
        const float* __restrict__ w1m_r,
        const float* __restrict__ w1x_l, const float* __restrict__ b1x,
        const float* __restrict__ w1x_r,
        const float* __restrict__ w2m_l,
        float* __restrict__ h1, float* __restrict__ z2) {
    __shared__ float sw[544];
    for (int t = threadIdx.x; t < 544; t += 256) {
        float v;
        if (t < 48)       v = w1m_l[t];
        else if (t < 72)  v = b1m[t - 48];
        else if (t < 120) v = w1m_r[t - 72];
        else if (t < 136) v = w1x_l[t - 120];
        else if (t < 144) v = b1x[t - 136];
        else if (t < 160) v = w1x_r[t - 144];
        else              v = w2m_l[t - 160];
        sw[t] = v;
    }
    __syncthreads();

    int i = blockIdx.x * blockDim.x + threadIdx.x;
    if (i >= N_NODES) return;

    float2 xi = x[i];
    float a0 = agg1s[2 * i], a1 = agg1s[2 * i + 1];
    unsigned m0u = agg1x[2 * i], m1u = agg1x[2 * i + 1];
    float m0 = m0u ? unflipf(m0u) : 0.0f;
    float m1 = m1u ? unflipf(m1u) : 0.0f;

    float hh[32];
#pragma unroll
    for (int k = 0; k < 24; k++) {
        float v = sw[48 + k] + sw[2 * k] * a0 + sw[2 * k + 1] * a1
                + sw[72 + 2 * k] * xi.x + sw[72 + 2 * k + 1] * xi.y;
        hh[k] = fmaxf(v, 0.0f);
    }
#pragma unroll
    for (int k = 0; k < 8; k++) {
        float v = sw[136 + k] + sw[120 + 2 * k] * m0 + sw[120 + 2 * k + 1] * m1
                + sw[144 + 2 * k] * xi.x + sw[144 + 2 * k + 1] * xi.y;
        hh[24 + k] = fmaxf(v, 0.0f);
    }

    float4* h1v = (float4*)(h1 + (size_t)i * 32);
#pragma unroll
    for (int q = 0; q < 8; q++)
        h1v[q] = make_float4(hh[4 * q], hh[4 * q + 1], hh[4 * q + 2], hh[4 * q + 3]);

#pragma unroll
    for (int j = 0; j < 12; j++) {
        float v = 0.0f;
#pragma unroll
        for (int k = 0; k < 32; k++) v += hh[k] * sw[160 + j * 32 + k];
        z2[(size_t)i * 12 + j] = v;
    }
}

// -------- K5a: layer-2 LDS aggregation, SPLIT=2 blocks/bucket, 32 lanes/edge, unroll 4 --------
__global__ __launch_bounds__(256) void k5a_agg2(
        const float* __restrict__ h1, const float* __restrict__ z2g,
        const int2* __restrict__ ebuf, const int* __restrict__ bucketBase,
        float* __restrict__ agg2s, unsigned* __restrict__ agg2x) {
    __shared__ unsigned s2x[256 * 32];   // 32 KB (h1 >= 0 -> uint order == float order)
    __shared__ float    s2s[256 * 12];   // 12 KB
    for (int t = threadIdx.x; t < 256 * 32; t += 256) s2x[t] = 0u;
    for (int t = threadIdx.x; t < 256 * 12; t += 256) s2s[t] = 0.0f;
    __syncthreads();

    int b = blockIdx.x >> 1, sp = blockIdx.x & 1;
    int eBeg = bucketBase[b], eEnd = bucketBase[b + 1];
    int half = (eEnd - eBeg + 1) >> 1;
    int beg = eBeg + sp * half;
    int end = min(eEnd, beg + half);

    int f  = threadIdx.x & 31;
    int eg = threadIdx.x >> 5;           // 8 edge-groups per block
    int e = beg + eg;
    for (; e + 24 < end; e += 32) {
        int2 r0 = ebuf[e], r1 = ebuf[e + 8], r2 = ebuf[e + 16], r3 = ebuf[e + 24];
        float v0 = h1[(size_t)(r0.x >> 8) * 32 + f];
        float v1 = h1[(size_t)(r1.x >> 8) * 32 + f];
        float v2 = h1[(size_t)(r2.x >> 8) * 32 + f];
        float v3 = h1[(size_t)(r3.x >> 8) * 32 + f];
        float z0 = 0, z1 = 0, z2v = 0, z3 = 0;
        if (f < 12) {
            z0 = z2g[(size_t)(r0.x >> 8) * 12 + f];
            z1 = z2g[(size_t)(r1.x >> 8) * 12 + f];
            z2v = z2g[(size_t)(r2.x >> 8) * 12 + f];
            z3 = z2g[(size_t)(r3.x >> 8) * 12 + f];
        }
        atomicMax(&s2x[(r0.x & 255) * 32 + f], __float_as_uint(v0));
        atomicMax(&s2x[(r1.x & 255) * 32 + f], __float_as_uint(v1));
        atomicMax(&s2x[(r2.x & 255) * 32 + f], __float_as_uint(v2));
        atomicMax(&s2x[(r3.x & 255) * 32 + f], __float_as_uint(v3));
        if (f < 12) {
            atomicAdd(&s2s[(r0.x & 255) * 12 + f], z0 * __int_as_float(r0.y));
            atomicAdd(&s2s[(r1.x & 255) * 12 + f], z1 * __int_as_float(r1.y));
            atomicAdd(&s2s[(r2.x & 255) * 12 + f], z2v * __int_as_float(r2.y));
            atomicAdd(&s2s[(r3.x & 255) * 12 + f], z3 * __int_as_float(r3.y));
        }
    }
    for (; e < end; e += 8) {
        int2 r = ebuf[e];
        int src = r.x >> 8, local = r.x & 255;
        float v = h1[(size_t)src * 32 + f];
        atomicMax(&s2x[local * 32 + f], __float_as_uint(v));
        if (f < 12) {
            float z = z2g[(size_t)src * 12 + f];
            atomicAdd(&s2s[local * 12 + f], z * __int_as_float(r.y));
        }
    }
    __syncthreads();

    // coalesced merge into global per-bucket regions
    int base_x = b * 8192;
    for (int u = threadIdx.x; u < 8192; u += 256) {
        unsigned m = s2x[u];
        if (m) atomicMax(&agg2x[base_x + u], m);
    }
    int base_s = b * 3072;
    for (int u = threadIdx.x; u < 3072; u += 256) {
        float v = s2s[u];
        if (v != 0.0f) atomicAdd(&agg2s[base_s + u], v);
    }
}

// ------------- K6: layer-2 epilogue + MLP head -> out -------------
__global__ __launch_bounds__(256) void k6_node2(
        const float* __restrict__ h1,
        const float* __restrict__ agg2s, const float* __restrict__ agg2x,
        const float* __restrict__ b2m, const float* __restrict__ w2m_r,
        const float* __restrict__ w2x_l, const float* __restrict__ b2x,
        const float* __restrict__ w2x_r,
        const float* __restrict__ w3, const float* __restrict__ b3,
        const float* __restrict__ w4, const float* __restrict__ b4,
        const float* __restrict__ w5, const float* __restrict__ b5,
        float* __restrict__ out) {
    __shared__ float sw[843];
    for (int t = threadIdx.x; t < 843; t += 256) {
        float v;
        if (t < 12)       v = b2m[t];
        else if (t < 396) v = w2m_r[t - 12];
        else if (t < 524) v = w2x_l[t - 396];
        else if (t < 528) v = b2x[t - 524];
        else if (t < 656) v = w2x_r[t - 528];
        else if (t < 784) v = w3[t - 656];
        else if (t < 792) v = b3[t - 784];
        else if (t < 832) v = w4[t - 792];
        else if (t < 837) v = b4[t - 832];
        else if (t < 842) v = w5[t - 837];
        else              v = b5[0];
        sw[t] = v;
    }
    __syncthreads();

    int i = blockIdx.x * blockDim.x + threadIdx.x;
    if (i >= N_NODES) return;

    float hh[32], ax[32];
    const float4* h1v = (const float4*)(h1 + (size_t)i * 32);
    const float4* axv = (const float4*)(agg2x + (size_t)i * 32);
#pragma unroll
    for (int q = 0; q < 8; q++) {
        float4 a = h1v[q];
        hh[4 * q] = a.x; hh[4 * q + 1] = a.y; hh[4 * q + 2] = a.z; hh[4 * q + 3] = a.w;
        float4 bb = axv[q];
        ax[4 * q] = bb.x; ax[4 * q + 1] = bb.y; ax[4 * q + 2] = bb.z; ax[4 * q + 3] = bb.w;
    }

    float h2[16];
#pragma unroll
    for (int j = 0; j < 12; j++) {
        float v = agg2s[(size_t)i * 12 + j] + sw[j];
#pragma unroll
        for (int k = 0; k < 32; k++) v += hh[k] * sw[12 + j * 32 + k];
        h2[j] = fmaxf(v, 0.0f);
    }
#pragma unroll
    for (int j = 0; j < 4; j++) {
        float v = sw[524 + j];
#pragma unroll
        for (int k = 0; k < 32; k++)
            v += ax[k] * sw[396 + j * 32 + k] + hh[k] * sw[528 + j * 32 + k];
        h2[12 + j] = fmaxf(v, 0.0f);
    }

    float t3[8];
#pragma unroll
    for (int j = 0; j < 8; j++) {
        float v = sw[784 + j];
#pragma unroll
        for (int k = 0; k < 16; k++) v += h2[k] * sw[656 + j * 16 + k];
        t3[j] = fmaxf(v, 0.0f);
    }
    float t4[5];
#pragma unroll
    for (int j = 0; j < 5; j++) {
        float v = sw[832 + j];
#pragma unroll
        for (int k = 0; k < 8; k++) v += t3[k] * sw[792 + j * 8 + k];
        t4[j] = fmaxf(v, 0.0f);
    }
    float o = sw[842];
#pragma unroll
    for (int k = 0; k < 5; k++) o += t4[k] * sw[837 + k];
    out[i] = o;
}

extern "C" void kernel_launch(void* const* d_in, const int* in_sizes, int n_in,
                              void* d_out, int out_size, void* d_ws, size_t ws_size,
                              hipStream_t stream) {
    const float* x     = (const float*)d_in[0];
    const int*   ei    = (const int*)d_in[1];
    const float* norm  = (const float*)d_in[2];
    const float* w1m_l = (const float*)d_in[3];
    const float* b1m   = (const float*)d_in[4];
    const float* w1m_r = (const float*)d_in[5];
    const float* w1x_l = (const float*)d_in[6];
    const float* b1x   = (const float*)d_in[7];
    const float* w1x_r = (const float*)d_in[8];
    const float* w2m_l = (const float*)d_in[9];
    const float* b2m   = (const float*)d_in[10];
    const float* w2m_r = (const float*)d_in[11];
    const float* w2x_l = (const float*)d_in[12];
    const float* b2x   = (const float*)d_in[13];
    const float* w2x_r = (const float*)d_in[14];
    const float* w3    = (const float*)d_in[15];
    const float* b3    = (const float*)d_in[16];
    const float* w4    = (const float*)d_in[17];
    const float* b4    = (const float*)d_in[18];
    const float* w5    = (const float*)d_in[19];
    const float* b5    = (const float*)d_in[20];
    float* out = (float*)d_out;

    // workspace layout (floats unless noted)
    char* ws = (char*)d_ws;
    int2*     ebuf  = (int2*)ws;                                   // 25.6 MB
    float*    h1    = (float*)(ws + (size_t)N_EDGES * 8);          // N_NODES*32
    float*    z2    = h1 + (size_t)N_NODES * 32;                   // N_NODES*12
    float*    aggs  = z2 + (size_t)N_NODES * 12;                   // 48*NPAD zeroed region:
    float*    agg1s = aggs;                                        //  2*NPAD
    unsigned* agg1x = (unsigned*)(agg1s + 2 * NPAD);               //  2*NPAD
    float*    agg2s = (float*)(agg1x + 2 * NPAD);                  // 12*NPAD
    unsigned* agg2x = (unsigned*)(agg2s + 12 * NPAD);              // 32*NPAD
    int*      total      = (int*)(agg2x + 32 * NPAD);              // NBUCK
    int*      bucketBase = total + NBUCK;                          // NBUCK+1
    int*      cursor     = bucketBase + NBUCK + 1;                 // NBUCK

    hipMemsetAsync(aggs, 0, (size_t)48 * NPAD * sizeof(float), stream);
    hipMemsetAsync(total, 0, NBUCK * sizeof(int), stream);

    k1_count  <<<K13_BLOCKS, 256, 0, stream>>>(ei, total);
    k2_scan   <<<1, 512, 0, stream>>>(total, bucketBase, cursor);
    k3_scatter<<<K13_BLOCKS, 256, 0, stream>>>(ei, norm, cursor, ebuf);
    k4a_agg1  <<<NBUCK * 2, 256, 0, stream>>>((const float2*)x, ebuf, bucketBase,
                                              agg1s, agg1x);
    k4b_node1 <<<(N_NODES + 255) / 256, 256, 0, stream>>>((const float2*)x, agg1s, agg1x,
                                                          w1m_l, b1m, w1m_r,
                                                          w1x_l, b1x, w1x_r,
                                                          w2m_l, h1, z2);
    k5a_agg2  <<<NBUCK * 2, 256, 0, stream>>>(h1, z2, ebuf, bucketBase,
                                              agg2s, agg2x);
    k6_node2  <<<(N_NODES + 255) / 256, 256, 0, stream>>>(h1, agg2s, (const float*)agg2x,
                                                          b2m, w2m_r, w2x_l, b2x, w2x_r,
                                                          w3, b3, w4, b4, w5, b5, out);
}